// Round 10
// baseline (329.199 us; speedup 1.0000x reference)
//
#include <hip/hip_runtime.h>
#include <math.h>

#define B_ 8
#define C_ 256
#define H_ 96
#define W_ 96
#define N_ 16
#define HW_ (H_*W_)

// workspace layout (floats)
#define WS_AS    0                        // a_s [B][H][W]        : 73728
#define WS_PK    (WS_AS + B_*HW_)         // pK  [C][160]         : 40960
                                          //   per channel: [t=0..8][n=0..15] = proto*ac, then [144+n] = ac^2
#define WS_SCALE (WS_PK + C_*160)         // scale [N]            : 16

typedef __attribute__((ext_vector_type(16))) float sf16;

// 16 FMAs, weight vector in SGPRs (one scalar operand per v_fma)
#define FMA16(A, f, wv) do { \
  A[0]=fmaf((f),(wv)[0],A[0]);   A[1]=fmaf((f),(wv)[1],A[1]); \
  A[2]=fmaf((f),(wv)[2],A[2]);   A[3]=fmaf((f),(wv)[3],A[3]); \
  A[4]=fmaf((f),(wv)[4],A[4]);   A[5]=fmaf((f),(wv)[5],A[5]); \
  A[6]=fmaf((f),(wv)[6],A[6]);   A[7]=fmaf((f),(wv)[7],A[7]); \
  A[8]=fmaf((f),(wv)[8],A[8]);   A[9]=fmaf((f),(wv)[9],A[9]); \
  A[10]=fmaf((f),(wv)[10],A[10]); A[11]=fmaf((f),(wv)[11],A[11]); \
  A[12]=fmaf((f),(wv)[12],A[12]); A[13]=fmaf((f),(wv)[13],A[13]); \
  A[14]=fmaf((f),(wv)[14],A[14]); A[15]=fmaf((f),(wv)[15],A[15]); \
} while (0)

// 4x s_load_dwordx16 + wait: 64 floats of weights -> SGPRs (earlyclobber!)
#define SLOADX4(q0,q1,q2,q3,kp,o0,o1,o2,o3) \
  asm volatile("s_load_dwordx16 %0, %4, " o0 "\n\t" \
               "s_load_dwordx16 %1, %4, " o1 "\n\t" \
               "s_load_dwordx16 %2, %4, " o2 "\n\t" \
               "s_load_dwordx16 %3, %4, " o3 "\n\t" \
               "s_waitcnt lgkmcnt(0)" \
               : "=&s"(q0), "=&s"(q1), "=&s"(q2), "=&s"(q3) : "s"(kp))

#define SLOADX2(q0,q1,kp,o0,o1) \
  asm volatile("s_load_dwordx16 %0, %2, " o0 "\n\t" \
               "s_load_dwordx16 %1, %2, " o1 "\n\t" \
               "s_waitcnt lgkmcnt(0)" \
               : "=&s"(q0), "=&s"(q1) : "s"(kp))

// ---------------- gates: a_c, folded+repacked conv weights, scale ----------------
__global__ __launch_bounds__(256) void gates_kernel(
    const float* __restrict__ proto, const float* __restrict__ Wc_w,
    const float* __restrict__ Wc_b,  const float* __restrict__ proto_w,
    float* __restrict__ ws) {
  const int n = blockIdx.x;    // prototype
  const int c = threadIdx.x;   // channel
  __shared__ float pbar[C_];
  __shared__ float red[256];

  const float* p = proto + ((size_t)n*C_ + c)*9;
  float s = 0.f, sq = 0.f;
#pragma unroll
  for (int t = 0; t < 9; ++t) { float v = p[t]; s += v; sq += v*v; }
  pbar[c] = s * (1.f/9.f);
  red[c]  = sq;
  __syncthreads();
  for (int off = 128; off > 0; off >>= 1) {
    if (c < off) red[c] += red[c + off];
    __syncthreads();
  }
  const float psq = red[0];   // ||proto_n||^2

  const float* wr = Wc_w + (size_t)c*C_;   // row c of Wc_w (y = x @ W^T)
  float a0 = Wc_b[c], a1 = 0.f, a2 = 0.f, a3 = 0.f;
#pragma unroll 4
  for (int k = 0; k < C_; k += 4) {
    a0 = fmaf(pbar[k+0], wr[k+0], a0);
    a1 = fmaf(pbar[k+1], wr[k+1], a1);
    a2 = fmaf(pbar[k+2], wr[k+2], a2);
    a3 = fmaf(pbar[k+3], wr[k+3], a3);
  }
  const float acc = (a0+a1)+(a2+a3);
  const float ac = 1.f / (1.f + expf(-acc));

  float* pK = ws + WS_PK;
#pragma unroll
  for (int t = 0; t < 9; ++t) pK[(size_t)c*160 + t*16 + n] = p[t]*ac;
  pK[(size_t)c*160 + 144 + n] = ac*ac;

  if (c == 0) {
    float m = -1e30f;
    for (int i = 0; i < N_; ++i) m = fmaxf(m, proto_w[i]);
    float se = 0.f;
    for (int i = 0; i < N_; ++i) se += expf(proto_w[i] - m);
    const float wn = expf(proto_w[n] - m) / se;
    const float pn = fmaxf(sqrtf(psq), 1e-6f);
    (ws + WS_SCALE)[n] = wn / pn;
  }
}

// ---------------- a_s stage 1: partial 1x1-conv dots, 8-way channel split ----------------
__global__ __launch_bounds__(256) void as1_kernel(
    const float* __restrict__ F, const float* __restrict__ sp_w,
    float* __restrict__ ws) {
  const int p  = blockIdx.x*256 + threadIdx.x;  // 0..B*HW-1
  const int s  = blockIdx.y;                    // channel slice 0..7
  const int b  = p / HW_;
  const int hw = p - b*HW_;
  const float* f = F + ((size_t)b*C_ + s*32)*HW_ + hw;
  const float* w = sp_w + s*32;
  float acc = 0.f;
#pragma unroll 8
  for (int c = 0; c < 32; ++c) acc = fmaf(f[(size_t)c*HW_], w[c], acc);
  atomicAdd(&ws[WS_AS + p], acc);
}

// ---------------- a_s stage 2: bias + sigmoid in place ----------------
__global__ __launch_bounds__(256) void as2_kernel(
    const float* __restrict__ sp_b, float* __restrict__ ws) {
  const int p = blockIdx.x*256 + threadIdx.x;
  const float v = ws[WS_AS + p] + sp_b[0];
  ws[WS_AS + p] = 1.f / (1.f + expf(-v));
}

// ---------------- main: gated conv + local norm + weighted sum ----------------
// Block (32,2,4) = 4 waves; each wave owns one 64-channel group for a 32x4
// pixel tile; each thread owns 2 vertical pixels (4x3 tap window). Weights
// arrive via s_load_dwordx16 into SGPRs (scalar pipe; zero LDS/VALU issue),
// consumed directly as the scalar operand of v_fma. Grid = 576 blocks -> all
// co-resident (~2.25 waves/SIMD), no tail.
__global__ __launch_bounds__(256) void main_kernel(
    const float* __restrict__ F, const float* __restrict__ ws,
    float* __restrict__ out) {
  const int tx = threadIdx.x;           // 0..31
  const int ty = threadIdx.y;           // 0..1
  const int wz = threadIdx.z;           // 0..3 channel group (one full wave each)
  const int px  = blockIdx.x*32 + tx;
  const int py0 = blockIdx.y*4 + ty*2;  // rows py0, py0+1
  const int b   = blockIdx.z;

  __shared__ float red[128][33];        // 16.9 KB reduce buffer

  // 4 rows x 3 cols tap window shared by the 2 vertical pixels
  const float* a_s = ws + WS_AS + (size_t)b*HW_;
  int   off[4][3];
  float asr[4][3];
#pragma unroll
  for (int r = 0; r < 4; ++r) {
#pragma unroll
    for (int dc = 0; dc < 3; ++dc) {
      const int yy = py0 - 1 + r, xx = px - 1 + dc;
      const bool valid = (yy >= 0) & (yy < H_) & (xx >= 0) & (xx < W_);
      const int cy = min(max(yy, 0), H_-1), cx = min(max(xx, 0), W_-1);
      off[r][dc] = cy*W_ + cx;
      asr[r][dc] = valid ? a_s[cy*W_ + cx] : 0.f;
    }
  }

  float an[2][16], asq[2][16];
#pragma unroll
  for (int p = 0; p < 2; ++p)
#pragma unroll
    for (int n = 0; n < N_; ++n) { an[p][n] = 0.f; asq[p][n] = 0.f; }

  // wave-uniform weight base (wz is uniform within a wave: blockDim.x*y == 64)
  const char* pkb = (const char*)(ws + WS_PK);
  const unsigned gbase = __builtin_amdgcn_readfirstlane((unsigned)(wz * 64 * 640));
  const float* bp = F + ((size_t)b*C_ + (wz<<6))*HW_;

#pragma unroll 1
  for (int ci = 0; ci < 64; ++ci) {
    const char* kp = pkb + gbase + ci*640;   // uniform -> SGPR pair
    // gated taps (4x3 window, 2 pixels)
    float fs[4][3];
#pragma unroll
    for (int r = 0; r < 4; ++r)
#pragma unroll
      for (int dc = 0; dc < 3; ++dc)
        fs[r][dc] = bp[off[r][dc]] * asr[r][dc];
    bp += HW_;
    float rs[4];
#pragma unroll
    for (int r = 0; r < 4; ++r)
      rs[r] = fmaf(fs[r][2], fs[r][2], fmaf(fs[r][1], fs[r][1], fs[r][0]*fs[r][0]));
    float s2[2];
    s2[0] = (rs[0] + rs[1]) + rs[2];
    s2[1] = (rs[1] + rs[2]) + rs[3];

    sf16 q0, q1, q2, q3;
    // taps 0..3  (t = dr*3+dc; pixel p uses fs[p+dr][dc])
    SLOADX4(q0, q1, q2, q3, kp, "0x0", "0x40", "0x80", "0xC0");
    __builtin_amdgcn_sched_barrier(0);
    FMA16(an[0], fs[0][0], q0); FMA16(an[1], fs[1][0], q0);   // t0 (0,0)
    FMA16(an[0], fs[0][1], q1); FMA16(an[1], fs[1][1], q1);   // t1 (0,1)
    FMA16(an[0], fs[0][2], q2); FMA16(an[1], fs[1][2], q2);   // t2 (0,2)
    FMA16(an[0], fs[1][0], q3); FMA16(an[1], fs[2][0], q3);   // t3 (1,0)
    // taps 4..7
    SLOADX4(q0, q1, q2, q3, kp, "0x100", "0x140", "0x180", "0x1C0");
    __builtin_amdgcn_sched_barrier(0);
    FMA16(an[0], fs[1][1], q0); FMA16(an[1], fs[2][1], q0);   // t4 (1,1)
    FMA16(an[0], fs[1][2], q1); FMA16(an[1], fs[2][2], q1);   // t5 (1,2)
    FMA16(an[0], fs[2][0], q2); FMA16(an[1], fs[3][0], q2);   // t6 (2,0)
    FMA16(an[0], fs[2][1], q3); FMA16(an[1], fs[3][1], q3);   // t7 (2,1)
    // tap 8 + ac2
    SLOADX2(q0, q1, kp, "0x200", "0x240");
    __builtin_amdgcn_sched_barrier(0);
    FMA16(an[0], fs[2][2], q0); FMA16(an[1], fs[3][2], q0);   // t8 (2,2)
    FMA16(asq[0], s2[0], q1);   FMA16(asq[1], s2[1], q1);     // ac2
  }

  // cross-wave channel reduce: 3 serial rounds through LDS (stride 33)
#pragma unroll 1
  for (int w = 1; w < 4; ++w) {
    __syncthreads();
    if (wz == w) {
#pragma unroll
      for (int p = 0; p < 2; ++p) {
        const int base = (ty*2 + p)*32 + tx;
#pragma unroll
        for (int n = 0; n < N_; ++n) {
          red[base][n]       = an[p][n];
          red[base][N_ + n]  = asq[p][n];
        }
      }
    }
    __syncthreads();
    if (wz == 0) {
#pragma unroll
      for (int p = 0; p < 2; ++p) {
        const int base = (ty*2 + p)*32 + tx;
#pragma unroll
        for (int n = 0; n < N_; ++n) {
          an[p][n]  += red[base][n];
          asq[p][n] += red[base][N_ + n];
        }
      }
    }
  }

  if (wz == 0) {
    const float* scale = ws + WS_SCALE;
#pragma unroll
    for (int p = 0; p < 2; ++p) {
      float o = 0.f;
#pragma unroll
      for (int n = 0; n < N_; ++n) {
        const float inv = rsqrtf(fmaxf(asq[p][n], 1e-6f));
        o += scale[n] * an[p][n] * inv;
      }
      out[(size_t)b*HW_ + (size_t)(py0 + p)*W_ + px] = o;
    }
  }
}

extern "C" void kernel_launch(void* const* d_in, const int* in_sizes, int n_in,
                              void* d_out, int out_size, void* d_ws, size_t ws_size,
                              hipStream_t stream) {
  const float* F       = (const float*)d_in[0];
  const float* proto   = (const float*)d_in[1];
  const float* Wc_w    = (const float*)d_in[2];
  const float* Wc_b    = (const float*)d_in[3];
  const float* sp_w    = (const float*)d_in[4];
  const float* sp_b    = (const float*)d_in[5];
  const float* proto_w = (const float*)d_in[6];
  float* out = (float*)d_out;
  float* ws  = (float*)d_ws;

  // zero the a_s accumulator (ws is poisoned before every launch)
  hipMemsetAsync((void*)(ws + WS_AS), 0, B_*HW_*sizeof(float), stream);
  gates_kernel<<<N_, C_, 0, stream>>>(proto, Wc_w, Wc_b, proto_w, ws);
  as1_kernel<<<dim3(B_*HW_/256, 8), 256, 0, stream>>>(F, sp_w, ws);
  as2_kernel<<<B_*HW_/256, 256, 0, stream>>>(sp_b, ws);
  main_kernel<<<dim3(3, 24, 8), dim3(32, 2, 4), 0, stream>>>(F, ws, out);
}